// Round 11
// baseline (113.458 us; speedup 1.0000x reference)
//
#include <hip/hip_runtime.h>
#include <hip/hip_bf16.h>
#include <stdint.h>

// SVM RBF layer: out[j] = b + sum_i a[i]*Y[i]*exp(-g*max(||x_i||^2+||z_j||^2-2*x_i.z_j, 0))
// N=8192 support vectors, M=4096 query points, d=512.
#define C2EXP (-0.0028179443441958f)   // -GAMMA * log2(e)

static constexpr int N_SV = 8192;
static constexpr int M_Q  = 4096;
static constexpr int DIM  = 512;
static constexpr int NP_A = N_SV / 16;   // 512 A panels (16 rows each)
static constexpr int NP_B = M_Q / 16;    // 256 B panels
static constexpr int NKT  = DIM / 32;    // 16 K-tiles

typedef __bf16 bf16x8 __attribute__((ext_vector_type(8)));
typedef float  f32x4  __attribute__((ext_vector_type(4)));

#define GLB const __attribute__((address_space(1))) void
#define LDS __attribute__((address_space(3))) void

// ---------------- prep v3: panel blocks -> region-ordered fragment layout ----
// One 256-thread block per 16-row panel. Xp/Zp hold 1-KB fragment blocks
// [kt][tile*16 + slot], each block = one 16x32 MFMA fragment in exact lane
// order (lane l: row l&15, k (l>>4)*8..+7, bytes l*16).
// Panel q (0..15 within its 256-row tile) is stored at SLOT so that each
// contiguous 8-KB half of a kt-slice equals one read-region of the main
// kernel's phase schedule:
//   A: slot = ((q>>2)&1)*8 + (q>>3)*4 + (q&3)   (half0 = all waves' m0-3)
//   B: slot = ((q>>1)&1)*8 + (q>>2)*2 + (q&1)   (half0 = all waves' n0-1)
__global__ __launch_bounds__(256) void svm_prep(
    const float* __restrict__ Z, const float* __restrict__ X,
    const float* __restrict__ Y, const float* __restrict__ a,
    const float* __restrict__ b,
    __bf16* __restrict__ Xp, __bf16* __restrict__ Zp,
    float* __restrict__ xn, float* __restrict__ zn, float* __restrict__ w,
    float* __restrict__ out)
{
    __shared__ float part[4][16];

    const int tid  = threadIdx.x;
    const int lane = tid & 63;
    const int wv   = tid >> 6;          // wave 0..3, owns kt = wv*4 .. wv*4+3
    const int pb   = blockIdx.x;
    const bool isA = (pb < NP_A);
    const int p    = isA ? pb : pb - NP_A;
    const float* src = (isA ? X : Z) + (size_t)p * 16 * DIM;
    __bf16* dst  = isA ? Xp : Zp;
    const int np = isA ? NP_A : NP_B;

    const int q    = p & 15;            // panel within its 256-row tile
    const int tile = p >> 4;
    const int slot = isA ? (((q >> 2) & 1) * 8 + (q >> 3) * 4 + (q & 3))
                         : (((q >> 1) & 1) * 8 + (q >> 2) * 2 + (q & 1));
    const size_t stIdx = (size_t)tile * 16 + slot;

    const int row = lane & 15;
    const int ch  = lane >> 4;

    float s = 0.0f;
    #pragma unroll
    for (int f = 0; f < 4; ++f) {
        const int kt = wv * 4 + f;
        const float4* rp = (const float4*)(src + (size_t)row * DIM + kt * 32 + ch * 8);
        float4 v0 = rp[0], v1 = rp[1];
        s += v0.x*v0.x + v0.y*v0.y + v0.z*v0.z + v0.w*v0.w
           + v1.x*v1.x + v1.y*v1.y + v1.z*v1.z + v1.w*v1.w;
        __bf16 h[8] = {(__bf16)v0.x, (__bf16)v0.y, (__bf16)v0.z, (__bf16)v0.w,
                       (__bf16)v1.x, (__bf16)v1.y, (__bf16)v1.z, (__bf16)v1.w};
        uint4 bits;
        __builtin_memcpy(&bits, h, 16);
        *(uint4*)((char*)dst + (((size_t)kt * np + stIdx) << 10) + lane * 16) = bits;
    }

    s += __shfl_xor(s, 16);
    s += __shfl_xor(s, 32);
    if (lane < 16) part[wv][lane] = s;
    __syncthreads();

    if (tid < 16) {
        const float t = part[0][tid] + part[1][tid] + part[2][tid] + part[3][tid];
        const int r = p * 16 + tid;
        if (isA) { xn[r] = t; w[r] = a[r] * Y[r]; }
        else     { zn[r] = t; out[r] = b[0]; }
    }
}

// ---------------- main: 256x256, 8 waves, 4-phase/kt counted-vmcnt pipeline --
// LDS [buf(2)][A 16KB | B 16KB], 1-KB frag blocks, ds_read = slot*1024+lane*16
// (conflict-free). Per kt (buf = t&1):
//   ph0: read A-mh0(4)+B-nh0(2)                 | 8 MFMA m0-3 x n0-1
//   ph1: read B-nh1(2); stage Ah0,Bh0[t+2]      | 8 MFMA m0-3 x n2-3
//   ph2: read A-mh1(4); stage Bh1[t+2]          | 8 MFMA m4-7 x n0-1
//   ph3: stage Ah1[t+2]                         | 8 MFMA m4-7 x n2-3; vmcnt(4)
// Each phase: [reads; stages; s_barrier; lgkmcnt(0); setprio(1); MFMA;
// setprio(0); s_barrier]. Stages target buf (t+2 has same parity), each
// 8-KB half overwritten >=2 barriers after its last read. Boundary vmcnt(4)
// leaves kt+2's 4 loads in flight (T4: never drain to 0); vmcnt(0) at t=14.
__global__ __launch_bounds__(512, 2) void svm_main(
    const __bf16* __restrict__ Xp, const __bf16* __restrict__ Zp,
    const float* __restrict__ xn, const float* __restrict__ zn,
    const float* __restrict__ w, float* __restrict__ out)
{
    __shared__ char Sh[65536];

    const int tid  = threadIdx.x;      // 0..511
    const int lane = tid & 63;
    const int wid  = tid >> 6;         // 0..7
    const int wr   = wid >> 2;         // M-group {0,1}  -> rows wr*128
    const int wc   = wid & 3;          // N-group {0..3} -> cols wc*64

    const int iBase = blockIdx.y * 256;
    const int jBase = blockIdx.x * 256;
    const int pbA   = blockIdx.y * 16;
    const int pbB   = blockIdx.x * 16;

    f32x4 acc[8][4];
    #pragma unroll
    for (int m = 0; m < 8; ++m)
        #pragma unroll
        for (int n = 0; n < 4; ++n)
            acc[m][n] = (f32x4)(0.0f);

    // stage one 8-KB half: op 0=A 1=B, h 0/1; dst buf = kt&1
    auto stageH = [&](const __bf16* Mp, int pb16, int kt, int op, int h, int np) {
        char* dst = (char*)Sh + (kt & 1) * 32768 + op * 16384 + h * 8192 + tid * 16;
        const char* s0 = (const char*)Mp + (((size_t)kt * np + pb16) << 10)
                       + h * 8192 + tid * 16;
        __builtin_amdgcn_global_load_lds((GLB*)s0, (LDS*)dst, 16, 0, 0);
    };

    // ---- prologue: kt0's 4 halves, then kt1's 4; wait oldest 4 (kt0) ----
    stageH(Xp, pbA, 0, 0, 0, NP_A);
    stageH(Xp, pbA, 0, 0, 1, NP_A);
    stageH(Zp, pbB, 0, 1, 0, NP_B);
    stageH(Zp, pbB, 0, 1, 1, NP_B);
    stageH(Xp, pbA, 1, 0, 0, NP_A);
    stageH(Xp, pbA, 1, 0, 1, NP_A);
    stageH(Zp, pbB, 1, 1, 0, NP_B);
    stageH(Zp, pbB, 1, 1, 1, NP_B);
    asm volatile("s_waitcnt vmcnt(4)" ::: "memory");
    __builtin_amdgcn_s_barrier();

    bf16x8 af[4], bf[4];

    #pragma unroll
    for (int t = 0; t < NKT; ++t) {
        const int buf = t & 1;
        const char* Ab = (const char*)Sh + buf * 32768 + lane * 16;
        const char* Bb = Ab + 16384;

        // ---- ph0: read A mh0 (slots wr*4+mi) + B nh0 (slots wc*2+j) ----
        #pragma unroll
        for (int mi = 0; mi < 4; ++mi)
            af[mi] = *(const bf16x8*)(Ab + (wr * 4 + mi) * 1024);
        #pragma unroll
        for (int j = 0; j < 2; ++j)
            bf[j] = *(const bf16x8*)(Bb + (wc * 2 + j) * 1024);
        __builtin_amdgcn_s_barrier();
        asm volatile("s_waitcnt lgkmcnt(0)" ::: "memory");
        __builtin_amdgcn_sched_barrier(0);
        __builtin_amdgcn_s_setprio(1);
        #pragma unroll
        for (int mi = 0; mi < 4; ++mi)
            #pragma unroll
            for (int n = 0; n < 2; ++n)
                acc[mi][n] = __builtin_amdgcn_mfma_f32_16x16x32_bf16(
                    af[mi], bf[n], acc[mi][n], 0, 0, 0);
        __builtin_amdgcn_s_setprio(0);
        __builtin_amdgcn_s_barrier();

        // ---- ph1: read B nh1 (slots 8+wc*2+j); stage Ah0,Bh0[t+2] ----
        #pragma unroll
        for (int j = 0; j < 2; ++j)
            bf[2 + j] = *(const bf16x8*)(Bb + (8 + wc * 2 + j) * 1024);
        if (t + 2 < NKT) {
            stageH(Xp, pbA, t + 2, 0, 0, NP_A);
            stageH(Zp, pbB, t + 2, 1, 0, NP_B);
        }
        __builtin_amdgcn_s_barrier();
        asm volatile("s_waitcnt lgkmcnt(0)" ::: "memory");
        __builtin_amdgcn_sched_barrier(0);
        __builtin_amdgcn_s_setprio(1);
        #pragma unroll
        for (int mi = 0; mi < 4; ++mi)
            #pragma unroll
            for (int n = 2; n < 4; ++n)
                acc[mi][n] = __builtin_amdgcn_mfma_f32_16x16x32_bf16(
                    af[mi], bf[n], acc[mi][n], 0, 0, 0);
        __builtin_amdgcn_s_setprio(0);
        __builtin_amdgcn_s_barrier();

        // ---- ph2: read A mh1 (slots 8+wr*4+mi); stage Bh1[t+2] ----
        #pragma unroll
        for (int mi = 0; mi < 4; ++mi)
            af[mi] = *(const bf16x8*)(Ab + (8 + wr * 4 + mi) * 1024);
        if (t + 2 < NKT)
            stageH(Zp, pbB, t + 2, 1, 1, NP_B);
        __builtin_amdgcn_s_barrier();
        asm volatile("s_waitcnt lgkmcnt(0)" ::: "memory");
        __builtin_amdgcn_sched_barrier(0);
        __builtin_amdgcn_s_setprio(1);
        #pragma unroll
        for (int mi = 0; mi < 4; ++mi)
            #pragma unroll
            for (int n = 0; n < 2; ++n)
                acc[4 + mi][n] = __builtin_amdgcn_mfma_f32_16x16x32_bf16(
                    af[mi], bf[n], acc[4 + mi][n], 0, 0, 0);
        __builtin_amdgcn_s_setprio(0);
        __builtin_amdgcn_s_barrier();

        // ---- ph3: stage Ah1[t+2]; MFMA m4-7 x n2-3; boundary vmcnt ----
        if (t + 2 < NKT)
            stageH(Xp, pbA, t + 2, 0, 1, NP_A);
        __builtin_amdgcn_s_barrier();
        asm volatile("s_waitcnt lgkmcnt(0)" ::: "memory");
        __builtin_amdgcn_sched_barrier(0);
        __builtin_amdgcn_s_setprio(1);
        #pragma unroll
        for (int mi = 0; mi < 4; ++mi)
            #pragma unroll
            for (int n = 2; n < 4; ++n)
                acc[4 + mi][n] = __builtin_amdgcn_mfma_f32_16x16x32_bf16(
                    af[mi], bf[n], acc[4 + mi][n], 0, 0, 0);
        __builtin_amdgcn_s_setprio(0);
        if (t < NKT - 2) {
            asm volatile("s_waitcnt vmcnt(4)" ::: "memory");   // keep kt+2 flying
        } else if (t == NKT - 2) {
            asm volatile("s_waitcnt vmcnt(0)" ::: "memory");   // tail drain
        }
        __builtin_amdgcn_s_barrier();
    }

    // ---- fused RBF epilogue ----
    // C frag (16x16x32): col = lane&15, row = (lane>>4)*4 + reg  [m89]
    const int rg   = lane >> 4;
    const int lcol = lane & 15;

    float znv[4];
    #pragma unroll
    for (int n = 0; n < 4; ++n)
        znv[n] = zn[jBase + wc * 64 + n * 16 + lcol];

    float cs[4] = {0.f, 0.f, 0.f, 0.f};
    #pragma unroll
    for (int m = 0; m < 8; ++m) {
        float wv[4], xv[4];
        #pragma unroll
        for (int r = 0; r < 4; ++r) {
            const int i = iBase + wr * 128 + m * 16 + rg * 4 + r;
            wv[r] = w[i];
            xv[r] = xn[i];
        }
        #pragma unroll
        for (int n = 0; n < 4; ++n)
            #pragma unroll
            for (int r = 0; r < 4; ++r) {
                float d = xv[r] + znv[n] - 2.0f * acc[m][n][r];
                d = fmaxf(d, 0.0f);
                cs[n] += wv[r] * exp2f(C2EXP * d);
            }
    }

    #pragma unroll
    for (int n = 0; n < 4; ++n) {
        const int j = jBase + wc * 64 + n * 16 + lcol;
        float c = cs[n];
        c += __shfl_xor(c, 16);
        c += __shfl_xor(c, 32);
        if (lane < 16) atomicAdd(out + j, c);
    }
}

// ---------------- launch -----------------------------------------------------
extern "C" void kernel_launch(void* const* d_in, const int* in_sizes, int n_in,
                              void* d_out, int out_size, void* d_ws, size_t ws_size,
                              hipStream_t stream)
{
    const float* Z = (const float*)d_in[0];   // inputs [4096, 512]
    const float* X = (const float*)d_in[1];   // X      [8192, 512]
    const float* Y = (const float*)d_in[2];   // Y      [8192, 1]
    const float* a = (const float*)d_in[3];   // a      [8192, 1]
    const float* b = (const float*)d_in[4];   // b      [1, 1]
    float* out = (float*)d_out;               // [4096, 1]

    char* ws = (char*)d_ws;
    __bf16* Xp = (__bf16*)ws;                                   // 8 MB
    __bf16* Zp = (__bf16*)(ws + 8ull * 1024 * 1024);            // 4 MB
    float*  xn = (float*)(ws + 12ull * 1024 * 1024);            // 32 KB
    float*  zn = xn + N_SV;                                     // 16 KB
    float*  w  = zn + M_Q;                                      // 32 KB

    svm_prep<<<NP_A + NP_B, 256, 0, stream>>>(Z, X, Y, a, b, Xp, Zp, xn, zn, w, out);
    svm_main<<<dim3(M_Q / 256, N_SV / 256), 512, 0, stream>>>(Xp, Zp, xn, zn, w, out);
}

// Round 12
// 111.474 us; speedup vs baseline: 1.0178x; 1.0178x over previous
//
#include <hip/hip_runtime.h>
#include <hip/hip_bf16.h>
#include <stdint.h>

// SVM RBF layer: out[j] = b + sum_i a[i]*Y[i]*exp(-g*max(||x_i||^2+||z_j||^2-2*x_i.z_j, 0))
// N=8192 support vectors, M=4096 query points, d=512.
#define C2EXP (-0.0028179443441958f)   // -GAMMA * log2(e)

static constexpr int N_SV = 8192;
static constexpr int M_Q  = 4096;
static constexpr int DIM  = 512;
static constexpr int NP_A = N_SV / 16;   // 512 A panels (16 rows each)
static constexpr int NP_B = M_Q / 16;    // 256 B panels
static constexpr int NKT  = DIM / 32;    // 16 K-tiles

typedef __bf16 bf16x8 __attribute__((ext_vector_type(8)));
typedef float  f32x4  __attribute__((ext_vector_type(4)));

#define GLB const __attribute__((address_space(1))) void
#define LDS __attribute__((address_space(3))) void

// ---------------- prep v3 (unchanged): region-ordered fragment layout -------
// One 256-thread block per 16-row panel. Xp/Zp hold 1-KB fragment blocks
// [kt][tile*16 + slot], each = one 16x32 MFMA fragment in exact lane order
// (lane l: row l&15, k (l>>4)*8..+7, bytes l*16).
//   A: slot = ((q>>2)&1)*8 + (q>>3)*4 + (q&3)   (half0 = all waves' m0-3)
//   B: slot = ((q>>1)&1)*8 + (q>>2)*2 + (q&1)   (half0 = all waves' n0-1)
__global__ __launch_bounds__(256) void svm_prep(
    const float* __restrict__ Z, const float* __restrict__ X,
    const float* __restrict__ Y, const float* __restrict__ a,
    const float* __restrict__ b,
    __bf16* __restrict__ Xp, __bf16* __restrict__ Zp,
    float* __restrict__ xn, float* __restrict__ zn, float* __restrict__ w,
    float* __restrict__ out)
{
    __shared__ float part[4][16];

    const int tid  = threadIdx.x;
    const int lane = tid & 63;
    const int wv   = tid >> 6;          // wave 0..3, owns kt = wv*4 .. wv*4+3
    const int pb   = blockIdx.x;
    const bool isA = (pb < NP_A);
    const int p    = isA ? pb : pb - NP_A;
    const float* src = (isA ? X : Z) + (size_t)p * 16 * DIM;
    __bf16* dst  = isA ? Xp : Zp;
    const int np = isA ? NP_A : NP_B;

    const int q    = p & 15;            // panel within its 256-row tile
    const int tile = p >> 4;
    const int slot = isA ? (((q >> 2) & 1) * 8 + (q >> 3) * 4 + (q & 3))
                         : (((q >> 1) & 1) * 8 + (q >> 2) * 2 + (q & 1));
    const size_t stIdx = (size_t)tile * 16 + slot;

    const int row = lane & 15;
    const int ch  = lane >> 4;

    float s = 0.0f;
    #pragma unroll
    for (int f = 0; f < 4; ++f) {
        const int kt = wv * 4 + f;
        const float4* rp = (const float4*)(src + (size_t)row * DIM + kt * 32 + ch * 8);
        float4 v0 = rp[0], v1 = rp[1];
        s += v0.x*v0.x + v0.y*v0.y + v0.z*v0.z + v0.w*v0.w
           + v1.x*v1.x + v1.y*v1.y + v1.z*v1.z + v1.w*v1.w;
        __bf16 h[8] = {(__bf16)v0.x, (__bf16)v0.y, (__bf16)v0.z, (__bf16)v0.w,
                       (__bf16)v1.x, (__bf16)v1.y, (__bf16)v1.z, (__bf16)v1.w};
        uint4 bits;
        __builtin_memcpy(&bits, h, 16);
        *(uint4*)((char*)dst + (((size_t)kt * np + stIdx) << 10) + lane * 16) = bits;
    }

    s += __shfl_xor(s, 16);
    s += __shfl_xor(s, 32);
    if (lane < 16) part[wv][lane] = s;
    __syncthreads();

    if (tid < 16) {
        const float t = part[0][tid] + part[1][tid] + part[2][tid] + part[3][tid];
        const int r = p * 16 + tid;
        if (isA) { xn[r] = t; w[r] = a[r] * Y[r]; }
        else     { zn[r] = t; out[r] = b[0]; }
    }
}

// ---------------- main: 256x256, 8 waves, 2 fat phases/kt, 1 barrier each ---
// Regions (per buf): Ah0 (A slots 0-7), Ah1 (8-15), Bh0, Bh1.
// ph0(t): stage Ah1[t+1]; read af m0-3 (Ah0) + bf n0-3 (Bh0+Bh1);
//         lgkm(0); vmcnt(4); BAR; 16 MFMA m0-3 x n0-3.
// ph1(t): stage Ah0,Bh0,Bh1[t+2]; read af m4-7 (Ah1);
//         lgkm(0); vmcnt(4); BAR; 16 MFMA m4-7 x n0-3 (bf reused in regs).
// Safety: every region overwrite is issued >=1 barrier after all waves
// drained (lgkm(0) precedes each BAR); per-wave vmcnt is globalized by the
// barrier after it. Ledger: prologue 7 issues -> vmcnt(4); steady 1+3/kt,
// vmcnt(4) at both boundaries; tail t=14: ph1 vmcnt(1); t=15: ph0 vmcnt(0),
// ph1 no wait/no barrier. Never drains to 0 until the tail (T4).
__global__ __launch_bounds__(512, 2) void svm_main(
    const __bf16* __restrict__ Xp, const __bf16* __restrict__ Zp,
    const float* __restrict__ xn, const float* __restrict__ zn,
    const float* __restrict__ w, float* __restrict__ out)
{
    __shared__ char Sh[65536];

    const int tid  = threadIdx.x;      // 0..511
    const int lane = tid & 63;
    const int wid  = tid >> 6;         // 0..7
    const int wr   = wid >> 2;         // M-group {0,1}  -> rows wr*128
    const int wc   = wid & 3;          // N-group {0..3} -> cols wc*64

    const int iBase = blockIdx.y * 256;
    const int jBase = blockIdx.x * 256;
    const int pbA   = blockIdx.y * 16;
    const int pbB   = blockIdx.x * 16;

    f32x4 acc[8][4];
    #pragma unroll
    for (int m = 0; m < 8; ++m)
        #pragma unroll
        for (int n = 0; n < 4; ++n)
            acc[m][n] = (f32x4)(0.0f);

    // stage one 8-KB region: op 0=A 1=B, h 0/1; dst buf = kt&1
    auto stageH = [&](const __bf16* Mp, int pb16, int kt, int op, int h, int np) {
        char* dst = (char*)Sh + (kt & 1) * 32768 + op * 16384 + h * 8192 + tid * 16;
        const char* s0 = (const char*)Mp + (((size_t)kt * np + pb16) << 10)
                       + h * 8192 + tid * 16;
        __builtin_amdgcn_global_load_lds((GLB*)s0, (LDS*)dst, 16, 0, 0);
    };
    auto stage3 = [&](int kt) {          // regions read in ph0: Ah0, Bh0, Bh1
        stageH(Xp, pbA, kt, 0, 0, NP_A);
        stageH(Zp, pbB, kt, 1, 0, NP_B);
        stageH(Zp, pbB, kt, 1, 1, NP_B);
    };
    auto stage1 = [&](int kt) {          // region read in ph1: Ah1
        stageH(Xp, pbA, kt, 0, 1, NP_A);
    };

    // ---- prologue: trio[0](3), Ah1[0](1), trio[1](3); retire trio[0] ----
    stage3(0);
    stage1(0);
    stage3(1);
    asm volatile("s_waitcnt vmcnt(4)" ::: "memory");
    __builtin_amdgcn_s_barrier();

    bf16x8 af[4], bf[4];

    #pragma unroll
    for (int t = 0; t < NKT; ++t) {
        const char* Ab = (const char*)Sh + (t & 1) * 32768 + lane * 16;
        const char* Bb = Ab + 16384;

        // ---- ph0: stage Ah1[t+1]; read af m0-3 + bf n0-3; 16 MFMA ----
        if (t + 1 < NKT) stage1(t + 1);
        #pragma unroll
        for (int mi = 0; mi < 4; ++mi)
            af[mi] = *(const bf16x8*)(Ab + (wr * 4 + mi) * 1024);
        #pragma unroll
        for (int j = 0; j < 2; ++j) {
            bf[j]     = *(const bf16x8*)(Bb + (wc * 2 + j) * 1024);
            bf[2 + j] = *(const bf16x8*)(Bb + (8 + wc * 2 + j) * 1024);
        }
        asm volatile("s_waitcnt lgkmcnt(0)" ::: "memory");
        if (t < NKT - 1) { asm volatile("s_waitcnt vmcnt(4)" ::: "memory"); }
        else             { asm volatile("s_waitcnt vmcnt(0)" ::: "memory"); }
        __builtin_amdgcn_s_barrier();
        __builtin_amdgcn_s_setprio(1);
        #pragma unroll
        for (int mi = 0; mi < 4; ++mi)
            #pragma unroll
            for (int n = 0; n < 4; ++n)
                acc[mi][n] = __builtin_amdgcn_mfma_f32_16x16x32_bf16(
                    af[mi], bf[n], acc[mi][n], 0, 0, 0);
        __builtin_amdgcn_s_setprio(0);

        // ---- ph1: stage trio[t+2]; read af m4-7; 16 MFMA (bf reused) ----
        if (t + 2 < NKT) stage3(t + 2);
        #pragma unroll
        for (int mi = 0; mi < 4; ++mi)
            af[mi] = *(const bf16x8*)(Ab + (8 + wr * 4 + mi) * 1024);
        asm volatile("s_waitcnt lgkmcnt(0)" ::: "memory");
        if (t < NKT - 2) {
            asm volatile("s_waitcnt vmcnt(4)" ::: "memory");
            __builtin_amdgcn_s_barrier();
        } else if (t == NKT - 2) {
            asm volatile("s_waitcnt vmcnt(1)" ::: "memory");
            __builtin_amdgcn_s_barrier();
        }
        // t == NKT-1: no stage, no wait, no barrier (epilogue follows)
        __builtin_amdgcn_s_setprio(1);
        #pragma unroll
        for (int mi = 0; mi < 4; ++mi)
            #pragma unroll
            for (int n = 0; n < 4; ++n)
                acc[4 + mi][n] = __builtin_amdgcn_mfma_f32_16x16x32_bf16(
                    af[mi], bf[n], acc[4 + mi][n], 0, 0, 0);
        __builtin_amdgcn_s_setprio(0);
    }

    // ---- fused RBF epilogue ----
    // C frag (16x16x32): col = lane&15, row = (lane>>4)*4 + reg  [m89]
    const int rg   = lane >> 4;
    const int lcol = lane & 15;

    float znv[4];
    #pragma unroll
    for (int n = 0; n < 4; ++n)
        znv[n] = zn[jBase + wc * 64 + n * 16 + lcol];

    float cs[4] = {0.f, 0.f, 0.f, 0.f};
    #pragma unroll
    for (int m = 0; m < 8; ++m) {
        float wv[4], xv[4];
        #pragma unroll
        for (int r = 0; r < 4; ++r) {
            const int i = iBase + wr * 128 + m * 16 + rg * 4 + r;
            wv[r] = w[i];
            xv[r] = xn[i];
        }
        #pragma unroll
        for (int n = 0; n < 4; ++n)
            #pragma unroll
            for (int r = 0; r < 4; ++r) {
                float d = xv[r] + znv[n] - 2.0f * acc[m][n][r];
                d = fmaxf(d, 0.0f);
                cs[n] += wv[r] * exp2f(C2EXP * d);
            }
    }

    #pragma unroll
    for (int n = 0; n < 4; ++n) {
        const int j = jBase + wc * 64 + n * 16 + lcol;
        float c = cs[n];
        c += __shfl_xor(c, 16);
        c += __shfl_xor(c, 32);
        if (lane < 16) atomicAdd(out + j, c);
    }
}

// ---------------- launch -----------------------------------------------------
extern "C" void kernel_launch(void* const* d_in, const int* in_sizes, int n_in,
                              void* d_out, int out_size, void* d_ws, size_t ws_size,
                              hipStream_t stream)
{
    const float* Z = (const float*)d_in[0];   // inputs [4096, 512]
    const float* X = (const float*)d_in[1];   // X      [8192, 512]
    const float* Y = (const float*)d_in[2];   // Y      [8192, 1]
    const float* a = (const float*)d_in[3];   // a      [8192, 1]
    const float* b = (const float*)d_in[4];   // b      [1, 1]
    float* out = (float*)d_out;               // [4096, 1]

    char* ws = (char*)d_ws;
    __bf16* Xp = (__bf16*)ws;                                   // 8 MB
    __bf16* Zp = (__bf16*)(ws + 8ull * 1024 * 1024);            // 4 MB
    float*  xn = (float*)(ws + 12ull * 1024 * 1024);            // 32 KB
    float*  zn = xn + N_SV;                                     // 16 KB
    float*  w  = zn + M_Q;                                      // 32 KB

    svm_prep<<<NP_A + NP_B, 256, 0, stream>>>(Z, X, Y, a, b, Xp, Zp, xn, zn, w, out);
    svm_main<<<dim3(M_Q / 256, N_SV / 256), 512, 0, stream>>>(Xp, Zp, xn, zn, w, out);
}